// Round 1
// baseline (172.888 us; speedup 1.0000x reference)
//
#include <hip/hip_runtime.h>
#include <cstdint>

// HypHawkes: attn = project(expmap0(softmax((project(expmap0(q))@W.T) @ project(expmap0(ctx)).T / d)))
// R11 = R10 + gemm_qw tile upsize: TM=TN=64 (343 TF-class) -> TM=128,TN=64,
//   grid (32,16)=512 blocks (2 blocks/CU). 8 MFMA per wave per K-step vs 4,
//   staging copies 3 vs 2 -> ~2x MFMA:staging ratio. A-staging reuses gemm_sc's
//   proven 128x32 pattern, B-staging reuses old gemm_qw's 64x32 pattern.
// Frozen from R9/R10: no __launch_bounds__ on GEMMs (LB(256) inflates VGPR 56->68
// and triples K-loop VALU — measured r3/r5/r7/r8 vs r1/r9), r1 staging shape, BK=32,
// bf16 intermediate scores, ws overlay (scores alias dead qn/Wb after gemm_qw).

typedef unsigned short ushort_t;
typedef __bf16 bf16x8 __attribute__((ext_vector_type(8)));
typedef float f32x4 __attribute__((ext_vector_type(4)));

__device__ __forceinline__ unsigned short f32_to_bf16(float f) {
  unsigned int u = __float_as_uint(f);
  u = (u + 0x7fffu + ((u >> 16) & 1u)) >> 16;  // RNE; inputs are finite
  return (unsigned short)u;
}

__device__ __forceinline__ void async_copy16(const void* g, void* s) {
  __builtin_amdgcn_global_load_lds(
      (const __attribute__((address_space(1))) void*)g,
      (__attribute__((address_space(3))) void*)s, 16, 0, 0);
}

// ---------------- fused prep: rownorm+expmap+project for q/ctx, cvt for W ---
// blocks [0,n): q rows; [n,n+m): ctx rows; [n+m, ...): W cvt (1024 floats each)
__global__ void prep_rows(const float* __restrict__ q, const float* __restrict__ ctx,
                          const float* __restrict__ W, ushort_t* __restrict__ qn,
                          ushort_t* __restrict__ cn, ushort_t* __restrict__ Wb,
                          const float* __restrict__ cptr, int n, int m) {
  const int b = blockIdx.x;
  const int tid = threadIdx.x;

  if (b >= n + m) {  // W conversion chunk
    int i = (b - n - m) * 256 + tid;
    float4 v = reinterpret_cast<const float4*>(W)[i];
    reinterpret_cast<ushort4*>(Wb)[i] =
        make_ushort4(f32_to_bf16(v.x), f32_to_bf16(v.y), f32_to_bf16(v.z), f32_to_bf16(v.w));
    return;
  }

  const int lane = tid & 63, w = tid >> 6;
  __shared__ float red[4];
  const float* x = (b < n) ? q + (size_t)b * 1024 : ctx + (size_t)(b - n) * 1024;
  ushort_t* out = (b < n) ? qn + (size_t)b * 1024 : cn + (size_t)(b - n) * 1024;

  float4 v = reinterpret_cast<const float4*>(x)[tid];
  float ss = v.x * v.x + v.y * v.y + v.z * v.z + v.w * v.w;
#pragma unroll
  for (int o = 32; o; o >>= 1) ss += __shfl_down(ss, o, 64);
  if (lane == 0) red[w] = ss;
  __syncthreads();
  ss = red[0] + red[1] + red[2] + red[3];

  const float c = *cptr;
  const float sqrtc = sqrtf(c);
  const float norm = fmaxf(sqrtf(ss), 1e-5f);            // expmap0 u_norm clamp
  const float t = tanhf(sqrtc * norm) / (sqrtc * norm);  // expmap scale
  const float en = fmaxf(t * norm, 1e-5f);               // |expmap0(u)| (project clamp)
  const float maxn = (1.0f - 4e-3f) / sqrtc;
  const float s = t * (en > maxn ? maxn / en : 1.0f);

  reinterpret_cast<ushort4*>(out)[tid] =
      make_ushort4(f32_to_bf16(v.x * s), f32_to_bf16(v.y * s),
                   f32_to_bf16(v.z * s), f32_to_bf16(v.w * s));
}

// ---------------- gemm1: qw = qn @ Wb^T, bf16 out -------------------------
// R11: TM=128, TN=64, BK=32, grid (32,16)=512 blocks, 12KB LDS.
// 4 waves in 2x2; each wave owns 64x32 of C: acc[4][2], 8 MFMA/K-step.
__global__ void gemm_qw(const ushort_t* __restrict__ A,
                        const ushort_t* __restrict__ B,
                        ushort_t* __restrict__ Cb, int K, int N) {
  __shared__ __align__(16) ushort_t As[128 * 32];
  __shared__ __align__(16) ushort_t Bs[64 * 32];

  const int tid = threadIdx.x;
  const int w = tid >> 6;
  const int lane = tid & 63;
  const int lane15 = lane & 15;
  const int quad = lane >> 4;
  const int wr = w >> 1, wc = w & 1;

  const size_t rowBase = (size_t)blockIdx.x * 128;
  const size_t colBase = (size_t)blockIdx.y * 64;

  const int srow = lane >> 2;        // 0..15
  const int scolE = (lane & 3) * 8;  // 0,8,16,24
  // A-staging: wave w covers rows [w*32, w*32+32) via two 16-row copies (gemm_sc pattern)
  const ushort_t* Ag = A + (rowBase + (size_t)(w * 32 + srow)) * K + scolE;
  // B-staging: wave w covers rows [w*16, w*16+16) via one copy (old gemm_qw pattern)
  const ushort_t* Bg = B + (colBase + (size_t)(w * 16 + srow)) * K + scolE;
  ushort_t* AsD = &As[w * 1024];
  ushort_t* BsD = &Bs[w * 512];

  f32x4 acc[4][2];
#pragma unroll
  for (int i = 0; i < 4; ++i)
#pragma unroll
    for (int j = 0; j < 2; ++j) acc[i][j] = f32x4{0.f, 0.f, 0.f, 0.f};

  for (int k0 = 0; k0 < K; k0 += 32) {
    async_copy16(Ag + k0, AsD);
    async_copy16(Ag + (size_t)16 * K + k0, AsD + 512);
    async_copy16(Bg + k0, BsD);
    __syncthreads();

    bf16x8 af[4], bv[2];
#pragma unroll
    for (int i = 0; i < 4; ++i)
      af[i] = *reinterpret_cast<const bf16x8*>(&As[(wr * 64 + i * 16 + lane15) * 32 + quad * 8]);
#pragma unroll
    for (int j = 0; j < 2; ++j)
      bv[j] = *reinterpret_cast<const bf16x8*>(&Bs[(wc * 32 + j * 16 + lane15) * 32 + quad * 8]);
#pragma unroll
    for (int i = 0; i < 4; ++i)
#pragma unroll
      for (int j = 0; j < 2; ++j)
        acc[i][j] = __builtin_amdgcn_mfma_f32_16x16x32_bf16(af[i], bv[j], acc[i][j], 0, 0, 0);
    __syncthreads();
  }

  // C/D layout: col = lane&15, row = quad*4 + reg
#pragma unroll
  for (int i = 0; i < 4; ++i)
#pragma unroll
    for (int j = 0; j < 2; ++j)
#pragma unroll
      for (int r = 0; r < 4; ++r) {
        size_t row = rowBase + (size_t)(wr * 64 + i * 16 + quad * 4 + r);
        size_t col = colBase + (size_t)(wc * 32 + j * 16 + lane15);
        Cb[row * N + col] = f32_to_bf16(acc[i][j][r]);
      }
}

// ---------------- gemm2: scoresB = bf16(qw @ cn^T) -------------------------
// r1 structure (VGPR 56, ~45us): TM=TN=128, BK=32, 16KB LDS. bf16 score stores.
__global__ void gemm_sc(const ushort_t* __restrict__ A,
                        const ushort_t* __restrict__ B,
                        ushort_t* __restrict__ Sb, int K, int N) {
  __shared__ __align__(16) ushort_t As[128 * 32];
  __shared__ __align__(16) ushort_t Bs[128 * 32];

  const int tid = threadIdx.x;
  const int w = tid >> 6;
  const int lane = tid & 63;
  const int lane15 = lane & 15;
  const int quad = lane >> 4;
  const int wr = w >> 1, wc = w & 1;

  const size_t rowBase = (size_t)blockIdx.x * 128;
  const size_t colBase = (size_t)blockIdx.y * 128;

  const int srow = lane >> 2;        // 0..15
  const int scolE = (lane & 3) * 8;  // 0,8,16,24
  const ushort_t* Ag = A + (rowBase + (size_t)(w * 32 + srow)) * K + scolE;
  const ushort_t* Bg = B + (colBase + (size_t)(w * 32 + srow)) * K + scolE;
  ushort_t* AsD = &As[(w * 2) * 512];
  ushort_t* BsD = &Bs[(w * 2) * 512];

  f32x4 acc[4][4];
#pragma unroll
  for (int i = 0; i < 4; ++i)
#pragma unroll
    for (int j = 0; j < 4; ++j) acc[i][j] = f32x4{0.f, 0.f, 0.f, 0.f};

  for (int k0 = 0; k0 < K; k0 += 32) {
    async_copy16(Ag + k0, AsD);
    async_copy16(Ag + (size_t)16 * K + k0, AsD + 512);
    async_copy16(Bg + k0, BsD);
    async_copy16(Bg + (size_t)16 * K + k0, BsD + 512);
    __syncthreads();

    bf16x8 af[4], bv[4];
#pragma unroll
    for (int i = 0; i < 4; ++i) {
      af[i] = *reinterpret_cast<const bf16x8*>(&As[(wr * 64 + i * 16 + lane15) * 32 + quad * 8]);
      bv[i] = *reinterpret_cast<const bf16x8*>(&Bs[(wc * 64 + i * 16 + lane15) * 32 + quad * 8]);
    }
#pragma unroll
    for (int i = 0; i < 4; ++i)
#pragma unroll
      for (int j = 0; j < 4; ++j)
        acc[i][j] = __builtin_amdgcn_mfma_f32_16x16x32_bf16(af[i], bv[j], acc[i][j], 0, 0, 0);
    __syncthreads();
  }

  // C/D layout: col = lane&15, row = quad*4 + reg; bf16 stores (half the bytes)
#pragma unroll
  for (int i = 0; i < 4; ++i)
#pragma unroll
    for (int j = 0; j < 4; ++j)
#pragma unroll
      for (int r = 0; r < 4; ++r) {
        size_t row = rowBase + (size_t)(wr * 64 + i * 16 + quad * 4 + r);
        size_t col = colBase + (size_t)(wc * 64 + j * 16 + lane15);
        Sb[row * N + col] = f32_to_bf16(acc[i][j][r]);
      }
}

// ---------------- softmax(row/d) + expmap0 + project: bf16 in, fp32 out ----
// No max pass: logits = scores/1024 are ~+/-2e-3; exp cannot overflow and
// max-subtraction is numerically irrelevant at the output tolerance.
__global__ void softmax_hyp(const ushort_t* __restrict__ S, float* __restrict__ out,
                            const float* __restrict__ cptr, float invd) {
  const int tid = threadIdx.x;
  const int lane = tid & 63, w = tid >> 6;
  __shared__ float redS[4], redQ[4];
  const ushort_t* rp = S + (size_t)blockIdx.x * 4096;
  float* op = out + (size_t)blockIdx.x * 4096;

  float e[16];
  float sum = 0.f, sq = 0.f;
#pragma unroll
  for (int i = 0; i < 2; ++i) {
    uint4 u = reinterpret_cast<const uint4*>(rp)[i * 256 + tid];  // 8 bf16
    unsigned int uw[4] = {u.x, u.y, u.z, u.w};
#pragma unroll
    for (int k = 0; k < 4; ++k) {
      float lo = __uint_as_float(uw[k] << 16);
      float hi = __uint_as_float(uw[k] & 0xffff0000u);
      float elo = __expf(lo * invd);
      float ehi = __expf(hi * invd);
      e[i * 8 + k * 2] = elo;
      e[i * 8 + k * 2 + 1] = ehi;
      sum += elo + ehi;
      sq += elo * elo + ehi * ehi;
    }
  }
#pragma unroll
  for (int o = 32; o; o >>= 1) {
    sum += __shfl_down(sum, o, 64);
    sq += __shfl_down(sq, o, 64);
  }
  if (lane == 0) { redS[w] = sum; redQ[w] = sq; }
  __syncthreads();
  sum = redS[0] + redS[1] + redS[2] + redS[3];
  sq = redQ[0] + redQ[1] + redQ[2] + redQ[3];

  const float c = *cptr;
  const float sqrtc = sqrtf(c);
  const float anorm = sqrtf(sq) / sum;       // |attn|
  const float an = fmaxf(anorm, 1e-5f);      // expmap0 clamp
  const float t = tanhf(sqrtc * an) / (sqrtc * an);
  const float pn = fmaxf(t * anorm, 1e-5f);  // |expmap0(attn)| (project clamp)
  const float maxn = (1.0f - 4e-3f) / sqrtc;
  const float g = t * (pn > maxn ? maxn / pn : 1.0f) / sum;

#pragma unroll
  for (int i = 0; i < 2; ++i)
#pragma unroll
    for (int k = 0; k < 2; ++k) {
      float4 o = make_float4(e[i * 8 + k * 4] * g, e[i * 8 + k * 4 + 1] * g,
                             e[i * 8 + k * 4 + 2] * g, e[i * 8 + k * 4 + 3] * g);
      reinterpret_cast<float4*>(op)[(i * 256 + tid) * 2 + k] = o;
    }
}

extern "C" void kernel_launch(void* const* d_in, const int* in_sizes, int n_in,
                              void* d_out, int out_size, void* d_ws, size_t ws_size,
                              hipStream_t stream) {
  const float* query = (const float*)d_in[0];
  const float* context = (const float*)d_in[1];
  const float* W = (const float*)d_in[2];
  const float* cptr = (const float*)d_in[3];

  const int d = 1024;
  const int n = in_sizes[0] / d;  // 4096
  const int m = in_sizes[1] / d;  // 4096

  // ws overlay (total 64MB): [cn 16MB][qw 16MB][qn 16MB][Wb 2MB]; after gemm_qw,
  // qn/Wb are dead and scoresB (32MB) reuses bytes [32MB, 64MB).
  ushort_t* cn = (ushort_t*)d_ws;            // m*d bf16
  ushort_t* qw = cn + (size_t)m * d;         // n*d
  ushort_t* qn = qw + (size_t)n * d;         // n*d (dead after gemm_qw)
  ushort_t* Wb = qn + (size_t)n * d;         // d*d (dead after gemm_qw)
  ushort_t* scoresB = qn;                    // n*m bf16, aliases qn+Wb region
  float* attn = (float*)d_out;               // n*m fp32 final output

  prep_rows<<<n + m + d * d / 1024, 256, 0, stream>>>(query, context, W, qn, cn, Wb, cptr, n, m);
  // qw = qn @ Wb^T : TM=128,TN=64, grid (32,16)=512 blocks
  gemm_qw<<<dim3(n / 128, d / 64), 256, 0, stream>>>(qn, Wb, qw, d, d);
  // scoresB = bf16(qw @ cn^T) : grid (32,32)=1024 blocks
  gemm_sc<<<dim3(n / 128, m / 128), 256, 0, stream>>>(qw, cn, scoresB, d, m);
  softmax_hyp<<<n, 256, 0, stream>>>(scoresB, attn, cptr, 1.0f / (float)d);
}

// Round 2
// 166.061 us; speedup vs baseline: 1.0411x; 1.0411x over previous
//
#include <hip/hip_runtime.h>
#include <cstdint>

// HypHawkes: attn = project(expmap0(softmax((project(expmap0(q))@W.T) @ project(expmap0(ctx)).T / d)))
// R12 = R11 + gemm_sc ported to the 256^2 8-phase template (T2+T3+T4+T5):
//   BM=BN=256, BK=64, 512 thr (2x4 waves), 128KB LDS double-buffered.
//   Per 64-K tile: 4 phases x 16 MFMA. Reads front-loaded in phases A+B;
//   mid-tile lgkmcnt(0)+raw-barrier guarantees all waves drained this buffer
//   before phases C/D stage tile t+2 into it (global_load_lds, counted vmcnt(8)
//   at tile tail only -- never drain to 0 in the loop). T2: st-swizzle
//   byte ^= (row&7)<<4 via pre-swizzled GLOBAL source (linear LDS dest) +
//   swizzled ds_read (rule #21). T5: setprio around MFMA clusters.
// Frozen: R11 gemm_qw (TM=128,TN=64; measured neutral vs 64^2 -- keep),
//   no __launch_bounds__ on 256-thr GEMMs, bf16 scores, ws overlay.

typedef unsigned short ushort_t;
typedef __bf16 bf16x8 __attribute__((ext_vector_type(8)));
typedef float f32x4 __attribute__((ext_vector_type(4)));

__device__ __forceinline__ unsigned short f32_to_bf16(float f) {
  unsigned int u = __float_as_uint(f);
  u = (u + 0x7fffu + ((u >> 16) & 1u)) >> 16;  // RNE; inputs are finite
  return (unsigned short)u;
}

__device__ __forceinline__ void async_copy16(const void* g, void* s) {
  __builtin_amdgcn_global_load_lds(
      (const __attribute__((address_space(1))) void*)g,
      (__attribute__((address_space(3))) void*)s, 16, 0, 0);
}

// ---------------- fused prep: rownorm+expmap+project for q/ctx, cvt for W ---
__global__ void prep_rows(const float* __restrict__ q, const float* __restrict__ ctx,
                          const float* __restrict__ W, ushort_t* __restrict__ qn,
                          ushort_t* __restrict__ cn, ushort_t* __restrict__ Wb,
                          const float* __restrict__ cptr, int n, int m) {
  const int b = blockIdx.x;
  const int tid = threadIdx.x;

  if (b >= n + m) {  // W conversion chunk
    int i = (b - n - m) * 256 + tid;
    float4 v = reinterpret_cast<const float4*>(W)[i];
    reinterpret_cast<ushort4*>(Wb)[i] =
        make_ushort4(f32_to_bf16(v.x), f32_to_bf16(v.y), f32_to_bf16(v.z), f32_to_bf16(v.w));
    return;
  }

  const int lane = tid & 63, w = tid >> 6;
  __shared__ float red[4];
  const float* x = (b < n) ? q + (size_t)b * 1024 : ctx + (size_t)(b - n) * 1024;
  ushort_t* out = (b < n) ? qn + (size_t)b * 1024 : cn + (size_t)(b - n) * 1024;

  float4 v = reinterpret_cast<const float4*>(x)[tid];
  float ss = v.x * v.x + v.y * v.y + v.z * v.z + v.w * v.w;
#pragma unroll
  for (int o = 32; o; o >>= 1) ss += __shfl_down(ss, o, 64);
  if (lane == 0) red[w] = ss;
  __syncthreads();
  ss = red[0] + red[1] + red[2] + red[3];

  const float c = *cptr;
  const float sqrtc = sqrtf(c);
  const float norm = fmaxf(sqrtf(ss), 1e-5f);            // expmap0 u_norm clamp
  const float t = tanhf(sqrtc * norm) / (sqrtc * norm);  // expmap scale
  const float en = fmaxf(t * norm, 1e-5f);               // |expmap0(u)| (project clamp)
  const float maxn = (1.0f - 4e-3f) / sqrtc;
  const float s = t * (en > maxn ? maxn / en : 1.0f);

  reinterpret_cast<ushort4*>(out)[tid] =
      make_ushort4(f32_to_bf16(v.x * s), f32_to_bf16(v.y * s),
                   f32_to_bf16(v.z * s), f32_to_bf16(v.w * s));
}

// ---------------- gemm1: qw = qn @ Wb^T, bf16 out (R11 structure) ----------
__global__ void gemm_qw(const ushort_t* __restrict__ A,
                        const ushort_t* __restrict__ B,
                        ushort_t* __restrict__ Cb, int K, int N) {
  __shared__ __align__(16) ushort_t As[128 * 32];
  __shared__ __align__(16) ushort_t Bs[64 * 32];

  const int tid = threadIdx.x;
  const int w = tid >> 6;
  const int lane = tid & 63;
  const int lane15 = lane & 15;
  const int quad = lane >> 4;
  const int wr = w >> 1, wc = w & 1;

  const size_t rowBase = (size_t)blockIdx.x * 128;
  const size_t colBase = (size_t)blockIdx.y * 64;

  const int srow = lane >> 2;        // 0..15
  const int scolE = (lane & 3) * 8;  // 0,8,16,24
  const ushort_t* Ag = A + (rowBase + (size_t)(w * 32 + srow)) * K + scolE;
  const ushort_t* Bg = B + (colBase + (size_t)(w * 16 + srow)) * K + scolE;
  ushort_t* AsD = &As[w * 1024];
  ushort_t* BsD = &Bs[w * 512];

  f32x4 acc[4][2];
#pragma unroll
  for (int i = 0; i < 4; ++i)
#pragma unroll
    for (int j = 0; j < 2; ++j) acc[i][j] = f32x4{0.f, 0.f, 0.f, 0.f};

  for (int k0 = 0; k0 < K; k0 += 32) {
    async_copy16(Ag + k0, AsD);
    async_copy16(Ag + (size_t)16 * K + k0, AsD + 512);
    async_copy16(Bg + k0, BsD);
    __syncthreads();

    bf16x8 af[4], bv[2];
#pragma unroll
    for (int i = 0; i < 4; ++i)
      af[i] = *reinterpret_cast<const bf16x8*>(&As[(wr * 64 + i * 16 + lane15) * 32 + quad * 8]);
#pragma unroll
    for (int j = 0; j < 2; ++j)
      bv[j] = *reinterpret_cast<const bf16x8*>(&Bs[(wc * 32 + j * 16 + lane15) * 32 + quad * 8]);
#pragma unroll
    for (int i = 0; i < 4; ++i)
#pragma unroll
      for (int j = 0; j < 2; ++j)
        acc[i][j] = __builtin_amdgcn_mfma_f32_16x16x32_bf16(af[i], bv[j], acc[i][j], 0, 0, 0);
    __syncthreads();
  }

#pragma unroll
  for (int i = 0; i < 4; ++i)
#pragma unroll
    for (int j = 0; j < 2; ++j)
#pragma unroll
      for (int r = 0; r < 4; ++r) {
        size_t row = rowBase + (size_t)(wr * 64 + i * 16 + quad * 4 + r);
        size_t col = colBase + (size_t)(wc * 32 + j * 16 + lane15);
        Cb[row * N + col] = f32_to_bf16(acc[i][j][r]);
      }
}

// ---------------- gemm2: scoresB = bf16(qw @ cn^T), 256^2 8-phase ----------
// BM=BN=256, BK=64, 8 waves (2M x 4N), per-wave 128x64 out = acc[8][4].
// LDS 128KB: As[2][256*64] + Bs[2][256*64] bf16, tile t in buf[t&1].
// Swizzle: element(row,col) stored at byte (row*128+col*2)^((row&7)<<4).

#define LDF(base, off) \
  (*reinterpret_cast<const bf16x8*>(reinterpret_cast<const char*>(base) + (off)))

// One 64-K tile: phases A,B (24 ds_reads + 2x16 MFMA), mid lgkm0+barrier,
// phases C,D (stage 8 loads of tile t+2 + 2x16 MFMA). Tail wait is outside.
#define SUBTILE(BUF, DOSTAGE, K0S)                                                        \
  do {                                                                                    \
    const ushort_t* As_ = &As[BUF][0];                                                    \
    const ushort_t* Bs_ = &Bs[BUF][0];                                                    \
    bf16x8 a0[4], b0[4], a1[4], c0[4], c1[4], b1[4];                                      \
    _Pragma("unroll") for (int mi = 0; mi < 4; ++mi) a0[mi] = LDF(As_, aO0 + mi * 2048);  \
    _Pragma("unroll") for (int ni = 0; ni < 4; ++ni) b0[ni] = LDF(Bs_, bO0 + ni * 2048);  \
    __builtin_amdgcn_s_setprio(1);                                                        \
    _Pragma("unroll") for (int mi = 0; mi < 4; ++mi)                                      \
      _Pragma("unroll") for (int ni = 0; ni < 4; ++ni)                                    \
        acc[mi][ni] = __builtin_amdgcn_mfma_f32_16x16x32_bf16(a0[mi], b0[ni], acc[mi][ni], 0, 0, 0); \
    __builtin_amdgcn_s_setprio(0);                                                        \
    _Pragma("unroll") for (int mi = 0; mi < 4; ++mi) a1[mi] = LDF(As_, aO0 + (4 + mi) * 2048); \
    _Pragma("unroll") for (int mi = 0; mi < 4; ++mi) c0[mi] = LDF(As_, aO1 + mi * 2048);  \
    _Pragma("unroll") for (int mi = 0; mi < 4; ++mi) c1[mi] = LDF(As_, aO1 + (4 + mi) * 2048); \
    _Pragma("unroll") for (int ni = 0; ni < 4; ++ni) b1[ni] = LDF(Bs_, bO1 + ni * 2048);  \
    __builtin_amdgcn_s_setprio(1);                                                        \
    _Pragma("unroll") for (int mi = 0; mi < 4; ++mi)                                      \
      _Pragma("unroll") for (int ni = 0; ni < 4; ++ni)                                    \
        acc[4 + mi][ni] = __builtin_amdgcn_mfma_f32_16x16x32_bf16(a1[mi], b0[ni], acc[4 + mi][ni], 0, 0, 0); \
    __builtin_amdgcn_s_setprio(0);                                                        \
    asm volatile("s_waitcnt lgkmcnt(0)" ::: "memory"); /* all reads of BUF drained */     \
    __builtin_amdgcn_sched_barrier(0);                                                    \
    __builtin_amdgcn_s_barrier();                      /* now safe to overwrite BUF */    \
    if (DOSTAGE) { /* phase C: stage A halves of tile t+2 into BUF */                     \
      async_copy16(Ag + (size_t)(K0S), &As[BUF][w * 512]);                                \
      async_copy16(Ag + (size_t)64 * K + (K0S), &As[BUF][4096 + w * 512]);                \
      async_copy16(Ag + (size_t)128 * K + (K0S), &As[BUF][8192 + w * 512]);               \
      async_copy16(Ag + (size_t)192 * K + (K0S), &As[BUF][12288 + w * 512]);              \
    }                                                                                     \
    __builtin_amdgcn_s_setprio(1);                                                        \
    _Pragma("unroll") for (int mi = 0; mi < 4; ++mi)                                      \
      _Pragma("unroll") for (int ni = 0; ni < 4; ++ni)                                    \
        acc[mi][ni] = __builtin_amdgcn_mfma_f32_16x16x32_bf16(c0[mi], b1[ni], acc[mi][ni], 0, 0, 0); \
    __builtin_amdgcn_s_setprio(0);                                                        \
    if (DOSTAGE) { /* phase D: stage B halves of tile t+2 into BUF */                     \
      async_copy16(Bg + (size_t)(K0S), &Bs[BUF][w * 512]);                                \
      async_copy16(Bg + (size_t)64 * K + (K0S), &Bs[BUF][4096 + w * 512]);                \
      async_copy16(Bg + (size_t)128 * K + (K0S), &Bs[BUF][8192 + w * 512]);               \
      async_copy16(Bg + (size_t)192 * K + (K0S), &Bs[BUF][12288 + w * 512]);              \
    }                                                                                     \
    __builtin_amdgcn_s_setprio(1);                                                        \
    _Pragma("unroll") for (int mi = 0; mi < 4; ++mi)                                      \
      _Pragma("unroll") for (int ni = 0; ni < 4; ++ni)                                    \
        acc[4 + mi][ni] = __builtin_amdgcn_mfma_f32_16x16x32_bf16(c1[mi], b1[ni], acc[4 + mi][ni], 0, 0, 0); \
    __builtin_amdgcn_s_setprio(0);                                                        \
  } while (0)

__global__ __launch_bounds__(512) void gemm_sc(const ushort_t* __restrict__ A,
                                               const ushort_t* __restrict__ B,
                                               ushort_t* __restrict__ Sb, int K, int N) {
  __shared__ __align__(16) ushort_t As[2][16384];  // 64 KB
  __shared__ __align__(16) ushort_t Bs[2][16384];  // 64 KB

  const int tid = threadIdx.x;
  const int w = tid >> 6;       // 0..7
  const int lane = tid & 63;
  const int l15 = lane & 15;
  const int quad = lane >> 4;
  const int wm = w >> 2;        // 0..1 (M half)
  const int wn = w & 3;         // 0..3 (N quarter)

  const size_t rowBase = (size_t)blockIdx.x * 256;
  const size_t colBase = (size_t)blockIdx.y * 256;

  // Staging: lane covers chunk c = k*512 + w*64 + lane of a 128-row half;
  // rlocal = c>>3, src col-chunk = (c&7)^(rlocal&7)  (inverse of read swizzle).
  const int colsw = (((lane & 7) ^ ((lane >> 3) & 7)) * 8);
  const ushort_t* Ag = A + (rowBase + (size_t)(w * 8 + (lane >> 3))) * K + colsw;
  const ushort_t* Bg = B + (colBase + (size_t)(w * 8 + (lane >> 3))) * K + colsw;

  // Frag-read byte offsets (swizzled); +mi*2048 walks M/N reps (bits>=11, xor-safe).
  const int axor = (l15 & 7) << 4;
  const int aO0 = (((wm * 128 + l15) * 128) + 0 * 64 + quad * 16) ^ axor;
  const int aO1 = (((wm * 128 + l15) * 128) + 1 * 64 + quad * 16) ^ axor;
  const int bO0 = (((wn * 64 + l15) * 128) + 0 * 64 + quad * 16) ^ axor;
  const int bO1 = (((wn * 64 + l15) * 128) + 1 * 64 + quad * 16) ^ axor;

  f32x4 acc[8][4];
#pragma unroll
  for (int mi = 0; mi < 8; ++mi)
#pragma unroll
    for (int ni = 0; ni < 4; ++ni) acc[mi][ni] = f32x4{0.f, 0.f, 0.f, 0.f};

  // Prologue: stage tile0 -> buf0 (8 loads), tile1 -> buf1 (8 loads); wait tile0.
#pragma unroll
  for (int hk = 0; hk < 4; ++hk)
    async_copy16(Ag + (size_t)(hk * 64) * K, &As[0][hk * 4096 + w * 512]);
#pragma unroll
  for (int hk = 0; hk < 4; ++hk)
    async_copy16(Bg + (size_t)(hk * 64) * K, &Bs[0][hk * 4096 + w * 512]);
#pragma unroll
  for (int hk = 0; hk < 4; ++hk)
    async_copy16(Ag + (size_t)(hk * 64) * K + 64, &As[1][hk * 4096 + w * 512]);
#pragma unroll
  for (int hk = 0; hk < 4; ++hk)
    async_copy16(Bg + (size_t)(hk * 64) * K + 64, &Bs[1][hk * 4096 + w * 512]);
  asm volatile("s_waitcnt vmcnt(8)" ::: "memory");  // tile0 landed (tile1 in flight)
  __builtin_amdgcn_s_barrier();

  // 16 K-tiles, processed in pairs (buf0 then buf1). Tile t stages tile t+2.
  for (int i = 0; i < 8; ++i) {
    const bool st = (i < 7);
    const int k0s = i * 128 + 128;  // k-offset of tile 2i+2
    SUBTILE(0, st, k0s);
    if (st) { asm volatile("s_waitcnt vmcnt(8)" ::: "memory"); }  // tile 2i+1 landed
    else    { asm volatile("s_waitcnt vmcnt(0)" ::: "memory"); }  // tile 15 landed
    __builtin_amdgcn_s_barrier();
    SUBTILE(1, st, k0s + 64);
    if (st) {
      asm volatile("s_waitcnt vmcnt(8)" ::: "memory");            // tile 2i+2 landed
      __builtin_amdgcn_s_barrier();
    }
  }

  // Epilogue: C/D layout col=l15, row=quad*4+r; bf16 stores.
#pragma unroll
  for (int mi = 0; mi < 8; ++mi)
#pragma unroll
    for (int ni = 0; ni < 4; ++ni)
#pragma unroll
      for (int r = 0; r < 4; ++r) {
        size_t row = rowBase + (size_t)(wm * 128 + mi * 16 + quad * 4 + r);
        size_t col = colBase + (size_t)(wn * 64 + ni * 16 + l15);
        Sb[row * N + col] = f32_to_bf16(acc[mi][ni][r]);
      }
}

// ---------------- softmax(row/d) + expmap0 + project: bf16 in, fp32 out ----
__global__ void softmax_hyp(const ushort_t* __restrict__ S, float* __restrict__ out,
                            const float* __restrict__ cptr, float invd) {
  const int tid = threadIdx.x;
  const int lane = tid & 63, w = tid >> 6;
  __shared__ float redS[4], redQ[4];
  const ushort_t* rp = S + (size_t)blockIdx.x * 4096;
  float* op = out + (size_t)blockIdx.x * 4096;

  float e[16];
  float sum = 0.f, sq = 0.f;
#pragma unroll
  for (int i = 0; i < 2; ++i) {
    uint4 u = reinterpret_cast<const uint4*>(rp)[i * 256 + tid];  // 8 bf16
    unsigned int uw[4] = {u.x, u.y, u.z, u.w};
#pragma unroll
    for (int k = 0; k < 4; ++k) {
      float lo = __uint_as_float(uw[k] << 16);
      float hi = __uint_as_float(uw[k] & 0xffff0000u);
      float elo = __expf(lo * invd);
      float ehi = __expf(hi * invd);
      e[i * 8 + k * 2] = elo;
      e[i * 8 + k * 2 + 1] = ehi;
      sum += elo + ehi;
      sq += elo * elo + ehi * ehi;
    }
  }
#pragma unroll
  for (int o = 32; o; o >>= 1) {
    sum += __shfl_down(sum, o, 64);
    sq += __shfl_down(sq, o, 64);
  }
  if (lane == 0) { redS[w] = sum; redQ[w] = sq; }
  __syncthreads();
  sum = redS[0] + redS[1] + redS[2] + redS[3];
  sq = redQ[0] + redQ[1] + redQ[2] + redQ[3];

  const float c = *cptr;
  const float sqrtc = sqrtf(c);
  const float anorm = sqrtf(sq) / sum;       // |attn|
  const float an = fmaxf(anorm, 1e-5f);      // expmap0 clamp
  const float t = tanhf(sqrtc * an) / (sqrtc * an);
  const float pn = fmaxf(t * anorm, 1e-5f);  // |expmap0(attn)| (project clamp)
  const float maxn = (1.0f - 4e-3f) / sqrtc;
  const float g = t * (pn > maxn ? maxn / pn : 1.0f) / sum;

#pragma unroll
  for (int i = 0; i < 2; ++i)
#pragma unroll
    for (int k = 0; k < 2; ++k) {
      float4 o = make_float4(e[i * 8 + k * 4] * g, e[i * 8 + k * 4 + 1] * g,
                             e[i * 8 + k * 4 + 2] * g, e[i * 8 + k * 4 + 3] * g);
      reinterpret_cast<float4*>(op)[(i * 256 + tid) * 2 + k] = o;
    }
}

extern "C" void kernel_launch(void* const* d_in, const int* in_sizes, int n_in,
                              void* d_out, int out_size, void* d_ws, size_t ws_size,
                              hipStream_t stream) {
  const float* query = (const float*)d_in[0];
  const float* context = (const float*)d_in[1];
  const float* W = (const float*)d_in[2];
  const float* cptr = (const float*)d_in[3];

  const int d = 1024;
  const int n = in_sizes[0] / d;  // 4096
  const int m = in_sizes[1] / d;  // 4096

  // ws overlay (total 64MB): [cn 16MB][qw 16MB][qn 16MB][Wb 2MB]; after gemm_qw,
  // qn/Wb are dead and scoresB (32MB) reuses bytes [32MB, 64MB).
  ushort_t* cn = (ushort_t*)d_ws;            // m*d bf16
  ushort_t* qw = cn + (size_t)m * d;         // n*d
  ushort_t* qn = qw + (size_t)n * d;         // n*d (dead after gemm_qw)
  ushort_t* Wb = qn + (size_t)n * d;         // d*d (dead after gemm_qw)
  ushort_t* scoresB = qn;                    // n*m bf16, aliases qn+Wb region
  float* attn = (float*)d_out;               // n*m fp32 final output

  prep_rows<<<n + m + d * d / 1024, 256, 0, stream>>>(query, context, W, qn, cn, Wb, cptr, n, m);
  // qw = qn @ Wb^T : TM=128,TN=64, grid (32,16)=512 blocks
  gemm_qw<<<dim3(n / 128, d / 64), 256, 0, stream>>>(qn, Wb, qw, d, d);
  // scoresB = bf16(qw @ cn^T) : 256^2 8-phase, grid (16,16)=256 blocks, 512 thr
  gemm_sc<<<dim3(n / 256, m / 256), 512, 0, stream>>>(qw, cn, scoresB, d, m);
  softmax_hyp<<<n, 256, 0, stream>>>(scoresB, attn, cptr, 1.0f / (float)d);
}

// Round 3
// 165.575 us; speedup vs baseline: 1.0442x; 1.0029x over previous
//
#include <hip/hip_runtime.h>
#include <cstdint>

// HypHawkes: attn = project(expmap0(softmax((project(expmap0(q))@W.T) @ project(expmap0(ctx)).T / d)))
// R13 = R12 + kernel merge for overlap: ctx-row prep (only consumed by gemm_sc)
//   is folded into the gemm_qw launch as extra blocks ([0,512)=GEMM tiles,
//   [512,512+m)=ctx rows). gemm_qw is MFMA/barrier-bound; ctx prep is pure BW ->
//   they co-schedule, hiding ~4.5us and removing one launch gap. prep_q now does
//   only q rows + W cvt.
// Accounting model (R12 rocprof): two 256MiB re-poison fills (~42us each) sit in
//   the timed region -> ~84us fixed floor; controllable kernel budget ~80us.
// Frozen: R12 gemm_sc (256^2 8-phase, bank-conflict=0, ~870-905TF at K=1024 =
//   reference level per m248), R11 gemm_qw structure, no __launch_bounds__ on
//   256-thr GEMMs, bf16 scores, ws overlay.

typedef unsigned short ushort_t;
typedef __bf16 bf16x8 __attribute__((ext_vector_type(8)));
typedef float f32x4 __attribute__((ext_vector_type(4)));

__device__ __forceinline__ unsigned short f32_to_bf16(float f) {
  unsigned int u = __float_as_uint(f);
  u = (u + 0x7fffu + ((u >> 16) & 1u)) >> 16;  // RNE; inputs are finite
  return (unsigned short)u;
}

__device__ __forceinline__ void async_copy16(const void* g, void* s) {
  __builtin_amdgcn_global_load_lds(
      (const __attribute__((address_space(1))) void*)g,
      (__attribute__((address_space(3))) void*)s, 16, 0, 0);
}

// ---------------- prep_q: q rownorm+expmap+project, W cvt --------------------
// blocks [0,n): q rows; [n, n+1024): W cvt chunks (1024 floats each)
__global__ void prep_q(const float* __restrict__ q, const float* __restrict__ W,
                       ushort_t* __restrict__ qn, ushort_t* __restrict__ Wb,
                       const float* __restrict__ cptr, int n) {
  const int b = blockIdx.x;
  const int tid = threadIdx.x;

  if (b >= n) {  // W conversion chunk
    int i = (b - n) * 256 + tid;
    float4 v = reinterpret_cast<const float4*>(W)[i];
    reinterpret_cast<ushort4*>(Wb)[i] =
        make_ushort4(f32_to_bf16(v.x), f32_to_bf16(v.y), f32_to_bf16(v.z), f32_to_bf16(v.w));
    return;
  }

  const int lane = tid & 63, w = tid >> 6;
  __shared__ float red[4];
  const float* x = q + (size_t)b * 1024;
  ushort_t* out = qn + (size_t)b * 1024;

  float4 v = reinterpret_cast<const float4*>(x)[tid];
  float ss = v.x * v.x + v.y * v.y + v.z * v.z + v.w * v.w;
#pragma unroll
  for (int o = 32; o; o >>= 1) ss += __shfl_down(ss, o, 64);
  if (lane == 0) red[w] = ss;
  __syncthreads();
  ss = red[0] + red[1] + red[2] + red[3];

  const float c = *cptr;
  const float sqrtc = sqrtf(c);
  const float norm = fmaxf(sqrtf(ss), 1e-5f);            // expmap0 u_norm clamp
  const float t = tanhf(sqrtc * norm) / (sqrtc * norm);  // expmap scale
  const float en = fmaxf(t * norm, 1e-5f);               // |expmap0(u)| (project clamp)
  const float maxn = (1.0f - 4e-3f) / sqrtc;
  const float s = t * (en > maxn ? maxn / en : 1.0f);

  reinterpret_cast<ushort4*>(out)[tid] =
      make_ushort4(f32_to_bf16(v.x * s), f32_to_bf16(v.y * s),
                   f32_to_bf16(v.z * s), f32_to_bf16(v.w * s));
}

// ---------------- qw_ctx: gemm_qw tiles + ctx prep, one launch ---------------
// blocks [0,nGemm): qw = qn @ Wb^T tile (R11 structure: TM=128,TN=64,BK=32);
// blocks [nGemm, nGemm+m): ctx row prep -> cn. Whole-block uniform branch.
__global__ void qw_ctx(const ushort_t* __restrict__ A,
                       const ushort_t* __restrict__ B,
                       ushort_t* __restrict__ Cb,
                       const float* __restrict__ ctx, ushort_t* __restrict__ cn,
                       const float* __restrict__ cptr, int K, int N, int nGemm) {
  __shared__ __align__(16) ushort_t As[128 * 32];
  __shared__ __align__(16) ushort_t Bs[64 * 32];

  const int tid = threadIdx.x;

  if (blockIdx.x >= nGemm) {  // ---------- ctx row prep ----------
    const int r = blockIdx.x - nGemm;
    const int lane = tid & 63, wv = tid >> 6;
    float* red = reinterpret_cast<float*>(As);  // reuse LDS
    const float* x = ctx + (size_t)r * 1024;
    ushort_t* out = cn + (size_t)r * 1024;

    float4 v = reinterpret_cast<const float4*>(x)[tid];
    float ss = v.x * v.x + v.y * v.y + v.z * v.z + v.w * v.w;
#pragma unroll
    for (int o = 32; o; o >>= 1) ss += __shfl_down(ss, o, 64);
    if (lane == 0) red[wv] = ss;
    __syncthreads();
    ss = red[0] + red[1] + red[2] + red[3];

    const float c = *cptr;
    const float sqrtc = sqrtf(c);
    const float norm = fmaxf(sqrtf(ss), 1e-5f);
    const float t = tanhf(sqrtc * norm) / (sqrtc * norm);
    const float en = fmaxf(t * norm, 1e-5f);
    const float maxn = (1.0f - 4e-3f) / sqrtc;
    const float s = t * (en > maxn ? maxn / en : 1.0f);

    reinterpret_cast<ushort4*>(out)[tid] =
        make_ushort4(f32_to_bf16(v.x * s), f32_to_bf16(v.y * s),
                     f32_to_bf16(v.z * s), f32_to_bf16(v.w * s));
    return;
  }

  // ---------- gemm_qw tile (R11 structure) ----------
  const int gx = blockIdx.x & 31;   // row-tile 0..31
  const int gy = blockIdx.x >> 5;   // col-tile 0..15
  const int w = tid >> 6;
  const int lane = tid & 63;
  const int lane15 = lane & 15;
  const int quad = lane >> 4;
  const int wr = w >> 1, wc = w & 1;

  const size_t rowBase = (size_t)gx * 128;
  const size_t colBase = (size_t)gy * 64;

  const int srow = lane >> 2;        // 0..15
  const int scolE = (lane & 3) * 8;  // 0,8,16,24
  const ushort_t* Ag = A + (rowBase + (size_t)(w * 32 + srow)) * K + scolE;
  const ushort_t* Bg = B + (colBase + (size_t)(w * 16 + srow)) * K + scolE;
  ushort_t* AsD = &As[w * 1024];
  ushort_t* BsD = &Bs[w * 512];

  f32x4 acc[4][2];
#pragma unroll
  for (int i = 0; i < 4; ++i)
#pragma unroll
    for (int j = 0; j < 2; ++j) acc[i][j] = f32x4{0.f, 0.f, 0.f, 0.f};

  for (int k0 = 0; k0 < K; k0 += 32) {
    async_copy16(Ag + k0, AsD);
    async_copy16(Ag + (size_t)16 * K + k0, AsD + 512);
    async_copy16(Bg + k0, BsD);
    __syncthreads();

    bf16x8 af[4], bv[2];
#pragma unroll
    for (int i = 0; i < 4; ++i)
      af[i] = *reinterpret_cast<const bf16x8*>(&As[(wr * 64 + i * 16 + lane15) * 32 + quad * 8]);
#pragma unroll
    for (int j = 0; j < 2; ++j)
      bv[j] = *reinterpret_cast<const bf16x8*>(&Bs[(wc * 32 + j * 16 + lane15) * 32 + quad * 8]);
#pragma unroll
    for (int i = 0; i < 4; ++i)
#pragma unroll
      for (int j = 0; j < 2; ++j)
        acc[i][j] = __builtin_amdgcn_mfma_f32_16x16x32_bf16(af[i], bv[j], acc[i][j], 0, 0, 0);
    __syncthreads();
  }

#pragma unroll
  for (int i = 0; i < 4; ++i)
#pragma unroll
    for (int j = 0; j < 2; ++j)
#pragma unroll
      for (int r = 0; r < 4; ++r) {
        size_t row = rowBase + (size_t)(wr * 64 + i * 16 + quad * 4 + r);
        size_t col = colBase + (size_t)(wc * 32 + j * 16 + lane15);
        Cb[row * N + col] = f32_to_bf16(acc[i][j][r]);
      }
}

// ---------------- gemm2: scoresB = bf16(qw @ cn^T), 256^2 8-phase ----------
// BM=BN=256, BK=64, 8 waves (2M x 4N), per-wave 128x64 out = acc[8][4].
// LDS 128KB: As[2][256*64] + Bs[2][256*64] bf16, tile t in buf[t&1].
// Swizzle: element(row,col) stored at byte (row*128+col*2)^((row&7)<<4).

#define LDF(base, off) \
  (*reinterpret_cast<const bf16x8*>(reinterpret_cast<const char*>(base) + (off)))

// One 64-K tile: phases A,B (24 ds_reads + 2x16 MFMA), mid lgkm0+barrier,
// phases C,D (stage 8 loads of tile t+2 + 2x16 MFMA). Tail wait is outside.
#define SUBTILE(BUF, DOSTAGE, K0S)                                                        \
  do {                                                                                    \
    const ushort_t* As_ = &As[BUF][0];                                                    \
    const ushort_t* Bs_ = &Bs[BUF][0];                                                    \
    bf16x8 a0[4], b0[4], a1[4], c0[4], c1[4], b1[4];                                      \
    _Pragma("unroll") for (int mi = 0; mi < 4; ++mi) a0[mi] = LDF(As_, aO0 + mi * 2048);  \
    _Pragma("unroll") for (int ni = 0; ni < 4; ++ni) b0[ni] = LDF(Bs_, bO0 + ni * 2048);  \
    __builtin_amdgcn_s_setprio(1);                                                        \
    _Pragma("unroll") for (int mi = 0; mi < 4; ++mi)                                      \
      _Pragma("unroll") for (int ni = 0; ni < 4; ++ni)                                    \
        acc[mi][ni] = __builtin_amdgcn_mfma_f32_16x16x32_bf16(a0[mi], b0[ni], acc[mi][ni], 0, 0, 0); \
    __builtin_amdgcn_s_setprio(0);                                                        \
    _Pragma("unroll") for (int mi = 0; mi < 4; ++mi) a1[mi] = LDF(As_, aO0 + (4 + mi) * 2048); \
    _Pragma("unroll") for (int mi = 0; mi < 4; ++mi) c0[mi] = LDF(As_, aO1 + mi * 2048);  \
    _Pragma("unroll") for (int mi = 0; mi < 4; ++mi) c1[mi] = LDF(As_, aO1 + (4 + mi) * 2048); \
    _Pragma("unroll") for (int ni = 0; ni < 4; ++ni) b1[ni] = LDF(Bs_, bO1 + ni * 2048);  \
    __builtin_amdgcn_s_setprio(1);                                                        \
    _Pragma("unroll") for (int mi = 0; mi < 4; ++mi)                                      \
      _Pragma("unroll") for (int ni = 0; ni < 4; ++ni)                                    \
        acc[4 + mi][ni] = __builtin_amdgcn_mfma_f32_16x16x32_bf16(a1[mi], b0[ni], acc[4 + mi][ni], 0, 0, 0); \
    __builtin_amdgcn_s_setprio(0);                                                        \
    asm volatile("s_waitcnt lgkmcnt(0)" ::: "memory"); /* all reads of BUF drained */     \
    __builtin_amdgcn_sched_barrier(0);                                                    \
    __builtin_amdgcn_s_barrier();                      /* now safe to overwrite BUF */    \
    if (DOSTAGE) { /* phase C: stage A halves of tile t+2 into BUF */                     \
      async_copy16(Ag + (size_t)(K0S), &As[BUF][w * 512]);                                \
      async_copy16(Ag + (size_t)64 * K + (K0S), &As[BUF][4096 + w * 512]);                \
      async_copy16(Ag + (size_t)128 * K + (K0S), &As[BUF][8192 + w * 512]);               \
      async_copy16(Ag + (size_t)192 * K + (K0S), &As[BUF][12288 + w * 512]);              \
    }                                                                                     \
    __builtin_amdgcn_s_setprio(1);                                                        \
    _Pragma("unroll") for (int mi = 0; mi < 4; ++mi)                                      \
      _Pragma("unroll") for (int ni = 0; ni < 4; ++ni)                                    \
        acc[mi][ni] = __builtin_amdgcn_mfma_f32_16x16x32_bf16(c0[mi], b1[ni], acc[mi][ni], 0, 0, 0); \
    __builtin_amdgcn_s_setprio(0);                                                        \
    if (DOSTAGE) { /* phase D: stage B halves of tile t+2 into BUF */                     \
      async_copy16(Bg + (size_t)(K0S), &Bs[BUF][w * 512]);                                \
      async_copy16(Bg + (size_t)64 * K + (K0S), &Bs[BUF][4096 + w * 512]);                \
      async_copy16(Bg + (size_t)128 * K + (K0S), &Bs[BUF][8192 + w * 512]);               \
      async_copy16(Bg + (size_t)192 * K + (K0S), &Bs[BUF][12288 + w * 512]);              \
    }                                                                                     \
    __builtin_amdgcn_s_setprio(1);                                                        \
    _Pragma("unroll") for (int mi = 0; mi < 4; ++mi)                                      \
      _Pragma("unroll") for (int ni = 0; ni < 4; ++ni)                                    \
        acc[4 + mi][ni] = __builtin_amdgcn_mfma_f32_16x16x32_bf16(c1[mi], b1[ni], acc[4 + mi][ni], 0, 0, 0); \
    __builtin_amdgcn_s_setprio(0);                                                        \
  } while (0)

__global__ __launch_bounds__(512) void gemm_sc(const ushort_t* __restrict__ A,
                                               const ushort_t* __restrict__ B,
                                               ushort_t* __restrict__ Sb, int K, int N) {
  __shared__ __align__(16) ushort_t As[2][16384];  // 64 KB
  __shared__ __align__(16) ushort_t Bs[2][16384];  // 64 KB

  const int tid = threadIdx.x;
  const int w = tid >> 6;       // 0..7
  const int lane = tid & 63;
  const int l15 = lane & 15;
  const int quad = lane >> 4;
  const int wm = w >> 2;        // 0..1 (M half)
  const int wn = w & 3;         // 0..3 (N quarter)

  const size_t rowBase = (size_t)blockIdx.x * 256;
  const size_t colBase = (size_t)blockIdx.y * 256;

  // Staging: lane covers chunk c = k*512 + w*64 + lane of a 128-row half;
  // rlocal = c>>3, src col-chunk = (c&7)^(rlocal&7)  (inverse of read swizzle).
  const int colsw = (((lane & 7) ^ ((lane >> 3) & 7)) * 8);
  const ushort_t* Ag = A + (rowBase + (size_t)(w * 8 + (lane >> 3))) * K + colsw;
  const ushort_t* Bg = B + (colBase + (size_t)(w * 8 + (lane >> 3))) * K + colsw;

  // Frag-read byte offsets (swizzled); +mi*2048 walks M/N reps (bits>=11, xor-safe).
  const int axor = (l15 & 7) << 4;
  const int aO0 = (((wm * 128 + l15) * 128) + 0 * 64 + quad * 16) ^ axor;
  const int aO1 = (((wm * 128 + l15) * 128) + 1 * 64 + quad * 16) ^ axor;
  const int bO0 = (((wn * 64 + l15) * 128) + 0 * 64 + quad * 16) ^ axor;
  const int bO1 = (((wn * 64 + l15) * 128) + 1 * 64 + quad * 16) ^ axor;

  f32x4 acc[8][4];
#pragma unroll
  for (int mi = 0; mi < 8; ++mi)
#pragma unroll
    for (int ni = 0; ni < 4; ++ni) acc[mi][ni] = f32x4{0.f, 0.f, 0.f, 0.f};

  // Prologue: stage tile0 -> buf0 (8 loads), tile1 -> buf1 (8 loads); wait tile0.
#pragma unroll
  for (int hk = 0; hk < 4; ++hk)
    async_copy16(Ag + (size_t)(hk * 64) * K, &As[0][hk * 4096 + w * 512]);
#pragma unroll
  for (int hk = 0; hk < 4; ++hk)
    async_copy16(Bg + (size_t)(hk * 64) * K, &Bs[0][hk * 4096 + w * 512]);
#pragma unroll
  for (int hk = 0; hk < 4; ++hk)
    async_copy16(Ag + (size_t)(hk * 64) * K + 64, &As[1][hk * 4096 + w * 512]);
#pragma unroll
  for (int hk = 0; hk < 4; ++hk)
    async_copy16(Bg + (size_t)(hk * 64) * K + 64, &Bs[1][hk * 4096 + w * 512]);
  asm volatile("s_waitcnt vmcnt(8)" ::: "memory");  // tile0 landed (tile1 in flight)
  __builtin_amdgcn_s_barrier();

  // 16 K-tiles, processed in pairs (buf0 then buf1). Tile t stages tile t+2.
  for (int i = 0; i < 8; ++i) {
    const bool st = (i < 7);
    const int k0s = i * 128 + 128;  // k-offset of tile 2i+2
    SUBTILE(0, st, k0s);
    if (st) { asm volatile("s_waitcnt vmcnt(8)" ::: "memory"); }  // tile 2i+1 landed
    else    { asm volatile("s_waitcnt vmcnt(0)" ::: "memory"); }  // tile 15 landed
    __builtin_amdgcn_s_barrier();
    SUBTILE(1, st, k0s + 64);
    if (st) {
      asm volatile("s_waitcnt vmcnt(8)" ::: "memory");            // tile 2i+2 landed
      __builtin_amdgcn_s_barrier();
    }
  }

  // Epilogue: C/D layout col=l15, row=quad*4+r; bf16 stores.
#pragma unroll
  for (int mi = 0; mi < 8; ++mi)
#pragma unroll
    for (int ni = 0; ni < 4; ++ni)
#pragma unroll
      for (int r = 0; r < 4; ++r) {
        size_t row = rowBase + (size_t)(wm * 128 + mi * 16 + quad * 4 + r);
        size_t col = colBase + (size_t)(wn * 64 + ni * 16 + l15);
        Sb[row * N + col] = f32_to_bf16(acc[mi][ni][r]);
      }
}

// ---------------- softmax(row/d) + expmap0 + project: bf16 in, fp32 out ----
__global__ void softmax_hyp(const ushort_t* __restrict__ S, float* __restrict__ out,
                            const float* __restrict__ cptr, float invd) {
  const int tid = threadIdx.x;
  const int lane = tid & 63, w = tid >> 6;
  __shared__ float redS[4], redQ[4];
  const ushort_t* rp = S + (size_t)blockIdx.x * 4096;
  float* op = out + (size_t)blockIdx.x * 4096;

  float e[16];
  float sum = 0.f, sq = 0.f;
#pragma unroll
  for (int i = 0; i < 2; ++i) {
    uint4 u = reinterpret_cast<const uint4*>(rp)[i * 256 + tid];  // 8 bf16
    unsigned int uw[4] = {u.x, u.y, u.z, u.w};
#pragma unroll
    for (int k = 0; k < 4; ++k) {
      float lo = __uint_as_float(uw[k] << 16);
      float hi = __uint_as_float(uw[k] & 0xffff0000u);
      float elo = __expf(lo * invd);
      float ehi = __expf(hi * invd);
      e[i * 8 + k * 2] = elo;
      e[i * 8 + k * 2 + 1] = ehi;
      sum += elo + ehi;
      sq += elo * elo + ehi * ehi;
    }
  }
#pragma unroll
  for (int o = 32; o; o >>= 1) {
    sum += __shfl_down(sum, o, 64);
    sq += __shfl_down(sq, o, 64);
  }
  if (lane == 0) { redS[w] = sum; redQ[w] = sq; }
  __syncthreads();
  sum = redS[0] + redS[1] + redS[2] + redS[3];
  sq = redQ[0] + redQ[1] + redQ[2] + redQ[3];

  const float c = *cptr;
  const float sqrtc = sqrtf(c);
  const float anorm = sqrtf(sq) / sum;       // |attn|
  const float an = fmaxf(anorm, 1e-5f);      // expmap0 clamp
  const float t = tanhf(sqrtc * an) / (sqrtc * an);
  const float pn = fmaxf(t * anorm, 1e-5f);  // |expmap0(attn)| (project clamp)
  const float maxn = (1.0f - 4e-3f) / sqrtc;
  const float g = t * (pn > maxn ? maxn / pn : 1.0f) / sum;

#pragma unroll
  for (int i = 0; i < 2; ++i)
#pragma unroll
    for (int k = 0; k < 2; ++k) {
      float4 o = make_float4(e[i * 8 + k * 4] * g, e[i * 8 + k * 4 + 1] * g,
                             e[i * 8 + k * 4 + 2] * g, e[i * 8 + k * 4 + 3] * g);
      reinterpret_cast<float4*>(op)[(i * 256 + tid) * 2 + k] = o;
    }
}

extern "C" void kernel_launch(void* const* d_in, const int* in_sizes, int n_in,
                              void* d_out, int out_size, void* d_ws, size_t ws_size,
                              hipStream_t stream) {
  const float* query = (const float*)d_in[0];
  const float* context = (const float*)d_in[1];
  const float* W = (const float*)d_in[2];
  const float* cptr = (const float*)d_in[3];

  const int d = 1024;
  const int n = in_sizes[0] / d;  // 4096
  const int m = in_sizes[1] / d;  // 4096

  // ws overlay (total 64MB): [cn 16MB][qw 16MB][qn 16MB][Wb 2MB]; after qw_ctx,
  // qn/Wb are dead and scoresB (32MB) reuses bytes [32MB, 64MB).
  ushort_t* cn = (ushort_t*)d_ws;            // m*d bf16
  ushort_t* qw = cn + (size_t)m * d;         // n*d
  ushort_t* qn = qw + (size_t)n * d;         // n*d (dead after qw_ctx)
  ushort_t* Wb = qn + (size_t)n * d;         // d*d (dead after qw_ctx)
  ushort_t* scoresB = qn;                    // n*m bf16, aliases qn+Wb region
  float* attn = (float*)d_out;               // n*m fp32 final output

  const int nGemm = (n / 128) * (d / 64);    // 512 gemm tiles

  // q rows + W cvt
  prep_q<<<n + d * d / 1024, 256, 0, stream>>>(query, W, qn, Wb, cptr, n);
  // qw = qn @ Wb^T (blocks [0,512)) overlapped with ctx prep (blocks [512,512+m))
  qw_ctx<<<nGemm + m, 256, 0, stream>>>(qn, Wb, qw, context, cn, cptr, d, d, nGemm);
  // scoresB = bf16(qw @ cn^T) : 256^2 8-phase, grid (16,16)=256 blocks, 512 thr
  gemm_sc<<<dim3(n / 256, m / 256), 512, 0, stream>>>(qw, cn, scoresB, d, m);
  softmax_hyp<<<n, 256, 0, stream>>>(scoresB, attn, cptr, 1.0f / (float)d);
}